// Round 1
// baseline (366.282 us; speedup 1.0000x reference)
//
#include <hip/hip_runtime.h>

#define NBINS 64

// quad_perm DPP: pure-VALU cross-lane within each 4-lane quad.
// CTRL = k|k<<2|k<<4|k<<6 broadcasts lane k of the quad.
template <int CTRL>
__device__ __forceinline__ float qperm(float x) {
    return __int_as_float(__builtin_amdgcn_update_dpp(
        0, __float_as_int(x), CTRL, 0xF, 0xF, true));
}

struct Group {            // one group = 16 rows; lane l owns row (l>>2),
    float4 y[4];          // bins [(l&3)*16 .. +15] as 4 float4s
    int    t, e;
};

__device__ __forceinline__ void load_group(Group& g,
                                           const float4* __restrict__ yv,
                                           const int* __restrict__ t,
                                           const int* __restrict__ e,
                                           int grp, int lane, int n_rows) {
    // flat float4 index: grp*1024/4 + lane*4 + c  (contiguous 4KiB per group)
    const size_t base = (size_t)grp * (16 * NBINS / 4) + lane * 4;
    #pragma unroll
    for (int c = 0; c < 4; ++c) g.y[c] = yv[base + c];
    const int row = grp * 16 + (lane >> 2);
    const int crow = min(row, n_rows - 1);
    g.t = t[crow];
    g.e = e[crow];
}

__device__ __forceinline__ float compute_group(const Group& g, int grp,
                                               int lane, float m1, float m2,
                                               float m3, int n_rows) {
    const int li = lane & 3;
    const int j0 = li * 16;           // first bin this lane owns
    const int tt = g.t;
    const int ee = g.e;
    const bool cen = (ee == 0);
    const float E10 = 22026.465794806718f;   // exp(10)

    // exp(pred): pred = (e==0 && j>=t) ? 10 : y  -> select OUTPUT (keeps
    // cmp/cndmask off the exp critical path). Safe without max-subtraction.
    float p[16];
    #pragma unroll
    for (int c = 0; c < 4; ++c) {
        const float4 y = g.y[c];
        #pragma unroll
        for (int k = 0; k < 4; ++k) {
            const int idx = c * 4 + k;
            const float yy = (k == 0) ? y.x : (k == 1) ? y.y
                           : (k == 2) ? y.z : y.w;
            const float ex = __expf(yy);
            const bool force = cen && (j0 + idx >= tt);
            p[idx] = force ? E10 : ex;
        }
    }
    // lane-local inclusive prefix over 16 elements (15 VALU adds, 16 rows/wave)
    #pragma unroll
    for (int idx = 1; idx < 16; ++idx) p[idx] += p[idx - 1];
    const float L = p[15];            // lane-local sum

    // cross-lane over the 4-lane quad: pure VALU (quad_perm broadcasts)
    const float b0 = qperm<0x00>(L);
    const float b1 = qperm<0x55>(L);
    const float b2 = qperm<0xAA>(L);
    const float b3 = qperm<0xFF>(L);
    const float excl  = fmaf(m1, b0, fmaf(m2, b1, m3 * b2));
    const float total = (b0 + b1) + (b2 + b3);
    const float rtot  = __builtin_amdgcn_rcpf(total);
    const float er    = excl * rtot;

    // analytic cumsum of target_dist (softmax of +-10 logits), linear in j:
    // cts(j) = (j+1)*lo + ((j>=t) ? j*slope + off : 0)
    const float s = 2.0611536224385579e-9f;   // exp(-20)
    const float k  = (ee == 1) ? 1.0f : (float)(NBINS - tt);
    const float hi = __builtin_amdgcn_rcpf(k + (64.0f - k) * s);
    const float lo = s * hi;
    const float hl = hi - lo;
    const float slope = cen ? hl : 0.0f;
    const float off   = cen ? (float)(1 - tt) * hl : hl;

    float acc = 0.0f;
    #pragma unroll
    for (int idx = 0; idx < 16; ++idx) {
        const int j = j0 + idx;
        const float m   = (j >= tt) ? fmaf((float)j, slope, off) : 0.0f;
        const float cts = fmaf((float)(j + 1), lo, m);
        const float d   = fmaf(p[idx], rtot, er - cts);   // cps - cts
        acc = fmaf(d, d, acc);
    }
    const int row = grp * 16 + (lane >> 2);
    return (row < n_rows) ? acc : 0.0f;
}

__global__ __launch_bounds__(256, 4) void survemd_kernel(
    const float* __restrict__ y_hat,
    const int* __restrict__ t,
    const int* __restrict__ e,
    float* __restrict__ out,
    int n_rows)
{
    const int lane = threadIdx.x & 63;
    const int wave_in_block = threadIdx.x >> 6;
    const int waves_per_block = blockDim.x >> 6;
    const int wave_id = blockIdx.x * waves_per_block + wave_in_block;
    const int total_waves = gridDim.x * waves_per_block;

    const float4* yv = (const float4*)y_hat;
    const int li = lane & 3;
    const float m1 = (li >= 1) ? 1.0f : 0.0f;
    const float m2 = (li >= 2) ? 1.0f : 0.0f;
    const float m3 = (li >= 3) ? 1.0f : 0.0f;

    const int ngroups = (n_rows + 15) >> 4;
    const int gpw     = (ngroups + total_waves - 1) / total_waves;
    const int begin   = wave_id * gpw;
    const int end     = min(begin + gpw, ngroups);

    float acc = 0.0f;
    if (begin < end) {
        Group A;
        load_group(A, yv, t, e, begin, lane, n_rows);
        for (int i = begin; i < end; ++i) {
            Group B;
            const int nxt = (i + 1 < end) ? i + 1 : i;
            load_group(B, yv, t, e, nxt, lane, n_rows);          // prefetch
            acc += compute_group(A, i, lane, m1, m2, m3, n_rows); // overlap
            A = B;
        }
    }

    // wave reduction
    #pragma unroll
    for (int off = 32; off >= 1; off >>= 1)
        acc += __shfl_down(acc, off, 64);

    __shared__ float wave_sums[8];
    if (lane == 0) wave_sums[wave_in_block] = acc;
    __syncthreads();
    if (threadIdx.x == 0) {
        float bsum = 0.0f;
        for (int w = 0; w < waves_per_block; ++w) bsum += wave_sums[w];
        atomicAdd(out, bsum * (1.0f / (float)n_rows));
    }
}

extern "C" void kernel_launch(void* const* d_in, const int* in_sizes, int n_in,
                              void* d_out, int out_size, void* d_ws, size_t ws_size,
                              hipStream_t stream) {
    const float* y_hat = (const float*)d_in[0];
    const int*   t     = (const int*)d_in[1];
    const int*   e     = (const int*)d_in[2];
    float* out = (float*)d_out;

    const int n_rows = in_sizes[1];  // B

    // The kernel only ever accumulates into out[0] (scalar loss); the
    // reference output is a single float. Zeroing the entire out_size
    // allocation was a ~1 GiB / ~161 us fill inside the timed graph —
    // zero exactly the 4 bytes the atomicAdd needs.
    (void)hipMemsetAsync(out, 0, sizeof(float), stream);

    const int block = 256;   // 4 waves/block
    const int grid  = 2048;  // 8192 waves; B=1M -> 8 groups (128 rows) each
    survemd_kernel<<<grid, block, 0, stream>>>(y_hat, t, e, out, n_rows);
}